// Round 2
// 1289.820 us; speedup vs baseline: 1.0179x; 1.0179x over previous
//
#include <hip/hip_runtime.h>

#define PI_F 3.14159265358979f
#define MT 16384   // B*T
#define EE 1024    // E
#define FF 4096    // 4E
#define NCH 8      // T-chunks for kv partial reduction
#define CHT (4096 / NCH)

typedef unsigned short u16;
typedef __attribute__((ext_vector_type(8))) short short8;
typedef __attribute__((ext_vector_type(4))) float f32x4;

__device__ __forceinline__ float bf2f(u16 u) {
  unsigned int v = ((unsigned int)u) << 16;
  float f;
  __builtin_memcpy(&f, &v, 4);
  return f;
}
__device__ __forceinline__ u16 f2bf(float f) {
  unsigned int x;
  __builtin_memcpy(&x, &f, 4);
  unsigned int r = x + 0x7fffu + ((x >> 16) & 1u);
  return (u16)(r >> 16);
}
// load element i from an external buffer whose dtype is runtime-detected
__device__ __forceinline__ float ldin(const void* p, long i, int f32) {
  return f32 ? ((const float*)p)[i] : bf2f(((const u16*)p)[i]);
}
// async global->LDS, 16B/lane; LDS dest = wave-uniform base + lane*16B
__device__ __forceinline__ void async16(const u16* g, u16* l) {
  __builtin_amdgcn_global_load_lds(
      (const __attribute__((address_space(1))) unsigned int*)g,
      (__attribute__((address_space(3))) unsigned int*)l, 16, 0, 0);
}

// ---------------------------------------------------------------------------
// dtype probe: bf16 N(0,1) data has no extreme-exponent u16s; fp32 data's low
// mantissa halves are ~uniform u16s -> ~45% extreme. flag: 0=bf16, 1=fp32.
// ---------------------------------------------------------------------------
__global__ __launch_bounds__(256) void detect_dtype(const u16* __restrict__ x,
                                                    int* __restrict__ flag) {
  const int tid = threadIdx.x;
  int cnt = 0;
  for (int i = tid; i < 2048; i += 256) {
    const int e = (x[i] >> 7) & 0xFF;
    if (e == 0 || e >= 0x90) cnt++;
  }
#pragma unroll
  for (int o = 32; o > 0; o >>= 1) cnt += __shfl_xor(cnt, o);
  __shared__ int s[4];
  if ((tid & 63) == 0) s[tid >> 6] = cnt;
  __syncthreads();
  if (tid == 0) flag[0] = (s[0] + s[1] + s[2] + s[3] > 200) ? 1 : 0;
}

// ---------------------------------------------------------------------------
// transpose + convert external weight: src[R][C] (bf16/f32 per flag) ->
// dst[C][R] bf16. block 256, grid (C/64, R/64)
// ---------------------------------------------------------------------------
__global__ __launch_bounds__(256) void transpose_in(
    const void* __restrict__ src, const int* __restrict__ flag,
    u16* __restrict__ dst, int R, int C) {
  __shared__ float tile[64][65];
  const int f = *flag;
  const int tx = threadIdx.x & 63, ty = threadIdx.x >> 6;
  const long c0 = (long)blockIdx.x * 64, r0 = (long)blockIdx.y * 64;
#pragma unroll
  for (int i = 0; i < 16; i++) {
    const int r = ty + i * 4;
    tile[r][tx] = ldin(src, (r0 + r) * (long)C + c0 + tx, f);
  }
  __syncthreads();
#pragma unroll
  for (int i = 0; i < 16; i++) {
    const int cc = ty + i * 4;
    dst[(c0 + cc) * (long)R + r0 + tx] = f2bf(tile[tx][cc]);
  }
}

// concat 3 external bias vectors (len 1024 each) into one f32 [3072]
__global__ __launch_bounds__(256) void concat3(
    const void* __restrict__ a, const void* __restrict__ b,
    const void* __restrict__ c, const int* __restrict__ flag,
    float* __restrict__ out) {
  const int i = blockIdx.x * 256 + threadIdx.x;
  const int fl = *flag;
  if (i < 1024) out[i] = ldin(a, i, fl);
  else if (i < 2048) out[i] = ldin(b, i - 1024, fl);
  else if (i < 3072) out[i] = ldin(c, i - 2048, fl);
}

// ---------------------------------------------------------------------------
// LayerNorm over last dim (1024) -> bf16 out. One block per row.
// xmode: 0 = bf16 ws buffer, 1 = f32 ws buffer, 2 = external (per flag)
// ---------------------------------------------------------------------------
__global__ __launch_bounds__(256) void ln_kernel(
    const void* __restrict__ xin, int xmode, const int* __restrict__ flag,
    const void* __restrict__ w, const void* __restrict__ b,
    u16* __restrict__ out) {
  const long row = blockIdx.x;
  const int tid = threadIdx.x;
  const int fl = *flag;
  const int xf = (xmode == 2) ? fl : xmode;
  float v[4];
  if (xf) {
    const float4 q = ((const float4*)((const float*)xin + row * EE))[tid];
    v[0] = q.x; v[1] = q.y; v[2] = q.z; v[3] = q.w;
  } else {
    const ushort4 u = ((const ushort4*)((const u16*)xin + row * EE))[tid];
    v[0] = bf2f(u.x); v[1] = bf2f(u.y); v[2] = bf2f(u.z); v[3] = bf2f(u.w);
  }
  float sum = v[0] + v[1] + v[2] + v[3];
  float sq = v[0] * v[0] + v[1] * v[1] + v[2] * v[2] + v[3] * v[3];
#pragma unroll
  for (int o = 32; o > 0; o >>= 1) {
    sum += __shfl_xor(sum, o);
    sq += __shfl_xor(sq, o);
  }
  __shared__ float s1[4], s2[4];
  const int wave = tid >> 6, lane = tid & 63;
  if (lane == 0) { s1[wave] = sum; s2[wave] = sq; }
  __syncthreads();
  sum = s1[0] + s1[1] + s1[2] + s1[3];
  sq = s2[0] + s2[1] + s2[2] + s2[3];
  const float mu = sum * (1.f / EE);
  const float var = sq * (1.f / EE) - mu * mu;
  const float rs = rsqrtf(var + 1e-5f);
  ushort4 o4;
  float r0 = (v[0] - mu) * rs * ldin(w, tid * 4 + 0, fl) + ldin(b, tid * 4 + 0, fl);
  float r1 = (v[1] - mu) * rs * ldin(w, tid * 4 + 1, fl) + ldin(b, tid * 4 + 1, fl);
  float r2 = (v[2] - mu) * rs * ldin(w, tid * 4 + 2, fl) + ldin(b, tid * 4 + 2, fl);
  float r3 = (v[3] - mu) * rs * ldin(w, tid * 4 + 3, fl) + ldin(b, tid * 4 + 3, fl);
  o4.x = f2bf(r0); o4.y = f2bf(r1); o4.z = f2bf(r2); o4.w = f2bf(r3);
  ((ushort4*)(out + row * EE))[tid] = o4;
}

// ---------------------------------------------------------------------------
// bf16 MFMA GEMM: C = act(A[M,K] @ Bt[N,K]^T + bias) (+res)
// T3 minimum-2-phase pipeline: double-buffered [128][32] LDS tiles (32 KiB),
// one __syncthreads per K-step placed AFTER the MFMAs so the next-tile
// global_load_lds latency hides under compute (vmcnt(0) drained by the
// barrier itself -> race-free by construction).
// act: 0 none, 1 relu, 2 gelu, 3 relu-if-col<2048 (fused qkv)
// resMode: 0 none, 1 f32 ws, 2 external (flag). outMode: 0 bf16 ws,
// 1 f32 ws, 2 external d_out (flag dtype) at element offset coff,
// 3 plane-major qkv split: planes 0,1 -> Cout + plane*M*1024 (bf16 rows of
//   1024), plane 2 -> Cv (separate base; v aliases x2's first half).
// ---------------------------------------------------------------------------
__global__ __launch_bounds__(256) void gemm_bf16(
    const u16* __restrict__ A, const u16* __restrict__ Bt,
    const void* __restrict__ bias, int biasF32,
    const void* __restrict__ res, int resMode,
    void* __restrict__ Cout, void* __restrict__ Cv, int outMode, long coff,
    const int* __restrict__ flag, int M, int N, int K, int act) {
  __shared__ u16 As[2][128 * 32];
  __shared__ u16 Bs[2][128 * 32];
  const int tid = threadIdx.x;
  const int lane = tid & 63;
  const int wave = tid >> 6;
  const int quad = lane >> 4;
  const int l16 = lane & 15;
  const int wm = (wave >> 1) * 64;
  const int wn = (wave & 1) * 64;
  const long bm = (long)blockIdx.x * 128;
  const long bn = (long)blockIdx.y * 128;

  f32x4 acc[4][4];
#pragma unroll
  for (int i = 0; i < 4; i++)
#pragma unroll
    for (int j = 0; j < 4; j++)
#pragma unroll
      for (int r = 0; r < 4; r++) acc[i][j][r] = 0.f;

  const int srow = tid >> 2;       // 0..63
  const int scol = (tid & 3) * 8;  // 0,8,16,24
  const u16* Ap = A + (bm + srow) * (long)K + scol;
  const u16* Bp = Bt + (bn + srow) * (long)K + scol;
  const long K64 = (long)64 * K;
  u16* As0 = &As[0][0];
  u16* Bs0 = &Bs[0][0];

  auto stage = [&](int b) {
    u16* Ad = As0 + b * 4096 + wave * 512;
    u16* Bd = Bs0 + b * 4096 + wave * 512;
    async16(Ap, Ad);
    async16(Ap + K64, Ad + 2048);
    async16(Bp, Bd);
    async16(Bp + K64, Bd + 2048);
    Ap += 32;
    Bp += 32;
  };
  auto compute = [&](int b) {
    const u16* Ab = As0 + b * 4096;
    const u16* Bb = Bs0 + b * 4096;
    short8 af[4], bfr[4];
#pragma unroll
    for (int i = 0; i < 4; i++)
      af[i] = *(const short8*)&Ab[(wm + i * 16 + l16) * 32 + quad * 8];
#pragma unroll
    for (int i = 0; i < 4; i++)
      bfr[i] = *(const short8*)&Bb[(wn + i * 16 + l16) * 32 + quad * 8];
#pragma unroll
    for (int mi = 0; mi < 4; mi++)
#pragma unroll
      for (int ni = 0; ni < 4; ni++)
        acc[mi][ni] = __builtin_amdgcn_mfma_f32_16x16x32_bf16(
            af[mi], bfr[ni], acc[mi][ni], 0, 0, 0);
  };

  // prologue: stage tile 0, drain, then steady state: stage t+1 / compute t
  stage(0);
  __syncthreads();
  const int nk = K >> 5;
  int buf = 0;
  for (int t = 1; t < nk; t++) {
    stage(buf ^ 1);      // issue next-tile loads first (in flight during MFMA)
    compute(buf);        // ds_read + MFMA current tile
    __syncthreads();     // drains vmcnt(0): next tile landed; reads published
    buf ^= 1;
  }
  compute(buf);          // last tile, nothing left to stage

  const int fl = *flag;
#pragma unroll
  for (int ni = 0; ni < 4; ni++) {
    const long gc = bn + wn + ni * 16 + l16;
    const float bvv = biasF32 ? ((const float*)bias)[gc] : ldin(bias, gc, fl);
#pragma unroll
    for (int mi = 0; mi < 4; mi++) {
      const long gr0 = bm + wm + mi * 16 + quad * 4;
#pragma unroll
      for (int r = 0; r < 4; r++) {
        float val = acc[mi][ni][r] + bvv;
        if (act == 1 || (act == 3 && gc < 2048)) val = fmaxf(val, 0.f);
        else if (act == 2) val = 0.5f * val * (1.f + erff(val * 0.70710678118654752f));
        const long row = gr0 + r;
        if (outMode == 3) {
          const long plane = gc >> 10;
          u16* dst = (plane == 2) ? (u16*)Cv
                                  : ((u16*)Cout + plane * ((long)M << 10));
          dst[(row << 10) + (gc & 1023)] = f2bf(val);
        } else {
          const long idx = row * (long)N + gc;
          float v2 = val;
          if (resMode == 1) v2 += ((const float*)res)[idx];
          else if (resMode == 2) v2 += ldin(res, idx, fl);
          if (outMode == 1 || (outMode == 2 && fl)) ((float*)Cout)[coff + idx] = v2;
          else ((u16*)Cout)[coff + idx] = f2bf(v2);
        }
      }
    }
  }
}

// ---------------------------------------------------------------------------
// kv partial: per (bh, chunk) accumulate kv_s/kv_c [64x64], ksum_s/c [64]
// kvpart[ch][bh][2][64][64], kspart[ch][bh][2][64]
// ---------------------------------------------------------------------------
__global__ __launch_bounds__(256) void kv_partial(
    const u16* __restrict__ k, const u16* __restrict__ v,
    float* __restrict__ kvpart, float* __restrict__ kspart) {
  const int bh = blockIdx.x;  // 0..63
  const int ch = blockIdx.y;  // 0..NCH-1
  const int b = bh >> 4, h = bh & 15;
  const int tid = threadIdx.x;
  __shared__ float kl[8][64], vl[8][64];
  const int dkq = tid >> 4;  // 0..15
  const int dvq = tid & 15;  // 0..15
  float accS[4][4] = {}, accC[4][4] = {};
  float ksS[4] = {}, ksC[4] = {};
  const int tt = tid >> 5;        // 0..7
  const int cc = (tid & 31) * 2;  // 0..62
  const long base = ((long)b * 4096 + ch * CHT) * EE + h * 64;
  for (int tb = 0; tb < CHT; tb += 8) {
    const long roff = base + (long)(tb + tt) * EE + cc;
    const unsigned int ku = *(const unsigned int*)(k + roff);
    const unsigned int vu = *(const unsigned int*)(v + roff);
    __syncthreads();
    kl[tt][cc] = bf2f((u16)ku);
    kl[tt][cc + 1] = bf2f((u16)(ku >> 16));
    vl[tt][cc] = bf2f((u16)vu);
    vl[tt][cc + 1] = bf2f((u16)(vu >> 16));
    __syncthreads();
#pragma unroll
    for (int j = 0; j < 8; j++) {
      const int t = ch * CHT + tb + j;
      float s, c;
      __sincosf((float)(t + 1) * (PI_F * 0.5f / 4096.f), &s, &c);
      float kk[4], vv[4];
#pragma unroll
      for (int i = 0; i < 4; i++) {
        kk[i] = kl[j][dkq * 4 + i];
        vv[i] = vl[j][dvq * 4 + i];
      }
#pragma unroll
      for (int i = 0; i < 4; i++) {
        const float ks_ = kk[i] * s, kc_ = kk[i] * c;
        ksS[i] += ks_;
        ksC[i] += kc_;
#pragma unroll
        for (int jj = 0; jj < 4; jj++) {
          accS[i][jj] += ks_ * vv[jj];
          accC[i][jj] += kc_ * vv[jj];
        }
      }
    }
  }
  float* outS = kvpart + (((long)ch * 64 + bh) * 2 + 0) * 4096;
  float* outC = outS + 4096;
#pragma unroll
  for (int i = 0; i < 4; i++)
#pragma unroll
    for (int jj = 0; jj < 4; jj++) {
      outS[(dkq * 4 + i) * 64 + dvq * 4 + jj] = accS[i][jj];
      outC[(dkq * 4 + i) * 64 + dvq * 4 + jj] = accC[i][jj];
    }
  if (dvq == 0) {
    float* oS = kspart + ((long)ch * 64 + bh) * 2 * 64;
#pragma unroll
    for (int i = 0; i < 4; i++) {
      oS[dkq * 4 + i] = ksS[i];
      oS[64 + dkq * 4 + i] = ksC[i];
    }
  }
}

// ---------------------------------------------------------------------------
__global__ __launch_bounds__(256) void kv_reduce(
    const float* __restrict__ kvpart, const float* __restrict__ kspart,
    float* __restrict__ kvcomb, float* __restrict__ kscomb) {
  const long KVTOT = 64L * 2 * 4096;  // 524288
  const long KSTOT = 64L * 2 * 64;    // 8192
  const long idx = (long)blockIdx.x * 256 + threadIdx.x;
  if (idx < KVTOT) {
    float s = 0.f;
#pragma unroll
    for (int chn = 0; chn < NCH; chn++) s += kvpart[chn * KVTOT + idx];
    kvcomb[idx] = s;
  } else {
    const long i2 = idx - KVTOT;
    if (i2 < KSTOT) {
      float s = 0.f;
#pragma unroll
      for (int chn = 0; chn < NCH; chn++) s += kspart[chn * KSTOT + i2];
      kscomb[i2] = s;
    }
  }
}

// ---------------------------------------------------------------------------
// apply: out[t,dv] = (s_t*(q.KVs)+c_t*(q.KVc))[dv] / max(s_t*q.kss+c_t*q.ksc,eps)
// ---------------------------------------------------------------------------
__global__ __launch_bounds__(256) void attn_apply(
    const u16* __restrict__ q, const float* __restrict__ kvcomb,
    const float* __restrict__ kscomb, u16* __restrict__ attn) {
  const int bh = blockIdx.x;
  const int b = bh >> 4, h = bh & 15;
  const int t0 = blockIdx.y * 64;
  const int tid = threadIdx.x;
  __shared__ float kvl[2][64][64];
  __shared__ float ksl[2][64];
  __shared__ float ql[64][66];

  const float4* kvsrc = (const float4*)(kvcomb + (long)bh * 8192);
  float4* kvdst = (float4*)&kvl[0][0][0];
#pragma unroll
  for (int i = 0; i < 8; i++) kvdst[tid + 256 * i] = kvsrc[tid + 256 * i];
  if (tid < 32) ((float4*)&ksl[0][0])[tid] = ((const float4*)(kscomb + (long)bh * 128))[tid];
  {
    const int r = tid >> 2;
    const int c = (tid & 3) * 16;
    const u16* qp = q + ((long)b * 4096 + t0 + r) * EE + h * 64 + c;
    const uint4 u0 = *(const uint4*)qp;
    const uint4 u1 = *(const uint4*)(qp + 8);
    unsigned int uu[8] = {u0.x, u0.y, u0.z, u0.w, u1.x, u1.y, u1.z, u1.w};
#pragma unroll
    for (int i = 0; i < 8; i++) {
      ql[r][c + 2 * i] = bf2f((u16)uu[i]);
      ql[r][c + 2 * i + 1] = bf2f((u16)(uu[i] >> 16));
    }
  }
  __syncthreads();

  const int tg = tid >> 4;
  const int dvq = tid & 15;
  const int dv0 = dvq * 4;

  float o1[4][4] = {}, o2[4][4] = {}, zs[4] = {}, zc[4] = {};
  for (int dk = 0; dk < 64; dk++) {
    const float ks0 = ksl[0][dk], ks1 = ksl[1][dk];
    float kv0[4], kv1[4];
#pragma unroll
    for (int j = 0; j < 4; j++) {
      kv0[j] = kvl[0][dk][dv0 + j];
      kv1[j] = kvl[1][dk][dv0 + j];
    }
#pragma unroll
    for (int it = 0; it < 4; it++) {
      const float qv = ql[tg + it * 16][dk];
      zs[it] += qv * ks0;
      zc[it] += qv * ks1;
#pragma unroll
      for (int j = 0; j < 4; j++) {
        o1[it][j] += qv * kv0[j];
        o2[it][j] += qv * kv1[j];
      }
    }
  }
#pragma unroll
  for (int it = 0; it < 4; it++) {
    const int t = t0 + tg + it * 16;
    float s, c;
    __sincosf((float)(t + 1) * (PI_F * 0.5f / 4096.f), &s, &c);
    const float z = s * zs[it] + c * zc[it];
    const float zinv = 1.f / fmaxf(z, 1e-6f);
    ushort4 o4;
    o4.x = f2bf((s * o1[it][0] + c * o2[it][0]) * zinv);
    o4.y = f2bf((s * o1[it][1] + c * o2[it][1]) * zinv);
    o4.z = f2bf((s * o1[it][2] + c * o2[it][2]) * zinv);
    o4.w = f2bf((s * o1[it][3] + c * o2[it][3]) * zinv);
    *(ushort4*)(attn + ((long)b * 4096 + t) * EE + h * 64 + dv0) = o4;
  }
}

// ---------------------------------------------------------------------------
extern "C" void kernel_launch(void* const* d_in, const int* in_sizes, int n_in,
                              void* d_out, int out_size, void* d_ws, size_t ws_size,
                              hipStream_t stream) {
  const void* x = d_in[0];
  const void* ln1w = d_in[1];
  const void* ln1b = d_in[2];
  const void* wq = d_in[3];
  const void* bq = d_in[4];
  const void* wk = d_in[5];
  const void* bk = d_in[6];
  const void* wv = d_in[7];
  const void* bv = d_in[8];
  const void* wo = d_in[9];
  const void* bo = d_in[10];
  const void* ln2w = d_in[11];
  const void* ln2b = d_in[12];
  const void* wfc = d_in[13];
  const void* bfc = d_in[14];
  const void* wproj = d_in[15];
  const void* bproj = d_in[16];

  char* ws = (char*)d_ws;
  size_t off = 0;
  auto alloc = [&](size_t bytes) -> char* {
    char* p = ws + off;
    off += (bytes + 255) & ~((size_t)255);
    return p;
  };
  // footprint identical to the proven 202-MiB baseline layout
  int* flag = (int*)alloc(256);
  u16* wqkvT = (u16*)alloc((size_t)3 * EE * EE * 2);  // [wq^T|wk^T|wv^T] rows
  u16* woT = (u16*)alloc((size_t)EE * EE * 2);
  u16* wfcT = (u16*)alloc((size_t)EE * FF * 2);
  u16* wprojT = (u16*)alloc((size_t)FF * EE * 2);
  float* qkvBias = (float*)alloc(3072 * 4);
  u16* h = (u16*)alloc((size_t)MT * EE * 2);       // 32 MiB
  float* x2 = (float*)alloc((size_t)MT * EE * 4);  // 64 MiB (residual, f32)
  u16* qk2 = (u16*)alloc((size_t)2 * MT * EE * 2); // 64 MiB: q,k planes
  float* kvpart = (float*)alloc((size_t)NCH * 64 * 2 * 64 * 64 * 4);
  float* kspart = (float*)alloc((size_t)NCH * 64 * 2 * 64 * 4);
  float* kvcomb = (float*)alloc((size_t)64 * 2 * 64 * 64 * 4);
  float* kscomb = (float*)alloc((size_t)64 * 2 * 64 * 4);
  const long PL = (long)MT * EE;  // plane stride (elems)
  u16* qb = qk2;            // plane 0
  u16* kb = qk2 + PL;       // plane 1
  u16* vb = (u16*)x2;       // v plane aliases x2[0:32MiB] — x2 dead until WO
                            // gemm, v dead before WO gemm overwrites it
  u16* attnb = kb;          // k-plane dead after kv_partial
  u16* g = qk2;             // q+k planes (64 MiB) dead after WO gemm
  (void)ws_size; (void)in_sizes; (void)n_in; (void)out_size;

  detect_dtype<<<1, 256, 0, stream>>>((const u16*)x, flag);

  transpose_in<<<dim3(16, 16), 256, 0, stream>>>(wq, flag, wqkvT, EE, EE);
  transpose_in<<<dim3(16, 16), 256, 0, stream>>>(wk, flag, wqkvT + (size_t)EE * EE, EE, EE);
  transpose_in<<<dim3(16, 16), 256, 0, stream>>>(wv, flag, wqkvT + (size_t)2 * EE * EE, EE, EE);
  transpose_in<<<dim3(16, 16), 256, 0, stream>>>(wo, flag, woT, EE, EE);
  transpose_in<<<dim3(64, 16), 256, 0, stream>>>(wfc, flag, wfcT, EE, FF);
  transpose_in<<<dim3(16, 64), 256, 0, stream>>>(wproj, flag, wprojT, FF, EE);
  concat3<<<12, 256, 0, stream>>>(bq, bk, bv, flag, qkvBias);

  ln_kernel<<<MT, 256, 0, stream>>>(x, 2, flag, ln1w, ln1b, h);

  // fused QKV: N=3072, relu on q,k planes only; plane-major output
  gemm_bf16<<<dim3(128, 24), 256, 0, stream>>>(h, wqkvT, qkvBias, 1, nullptr, 0,
                                               qk2, vb, 3, 0, flag, MT, 3072, EE, 3);

  kv_partial<<<dim3(64, NCH), 256, 0, stream>>>(kb, vb, kvpart, kspart);
  kv_reduce<<<2080, 256, 0, stream>>>(kvpart, kspart, kvcomb, kscomb);
  attn_apply<<<dim3(64, 64), 256, 0, stream>>>(qb, kvcomb, kscomb, attnb);

  gemm_bf16<<<dim3(128, 8), 256, 0, stream>>>(attnb, woT, bo, 0, x, 2, x2, nullptr,
                                              1, 0, flag, MT, EE, EE, 0);
  ln_kernel<<<MT, 256, 0, stream>>>(x2, 1, flag, ln2w, ln2b, h);

  for (int c = 0; c < 2; c++) {
    const long ro = (long)c * 8192 * EE;
    gemm_bf16<<<dim3(64, 32), 256, 0, stream>>>(h + ro, wfcT, bfc, 0, nullptr, 0,
                                                g, nullptr, 0, 0, flag, 8192, FF, EE, 2);
    gemm_bf16<<<dim3(64, 8), 256, 0, stream>>>(g, wprojT, bproj, 0, x2 + ro, 1,
                                               d_out, nullptr, 2, ro, flag, 8192, EE, FF, 0);
  }
}